// Round 15
// baseline (484.383 us; speedup 1.0000x reference)
//
#include <hip/hip_runtime.h>
#include <hip/hip_bf16.h>
#include <cmath>

namespace {

constexpr int CB = 4, CS = 1024, CD = 1024, CH = 4, CE = 32, CF = 512;
constexpr int CKS = 8, CNC = 10, CDK = 256, CDKV = 256;
constexpr int CT = CB * CS;
constexpr int CQKV = 1536;
constexpr float CEPS = 1e-6f;

using hb = __hip_bfloat16;
typedef __bf16 bf16x8 __attribute__((ext_vector_type(8)));
typedef float f32x4 __attribute__((ext_vector_type(4)));

#define WAITV4 asm volatile("s_waitcnt vmcnt(4)" ::: "memory")
#define WAITV0 asm volatile("s_waitcnt vmcnt(0)" ::: "memory")
#define CFENCE asm volatile("" ::: "memory")

__device__ __forceinline__ void gload16(const void* g, void* l) {
    __builtin_amdgcn_global_load_lds((const __attribute__((address_space(1))) void*)g,
                                     (__attribute__((address_space(3))) void*)l, 16, 0, 0);
}

__device__ __forceinline__ unsigned short f2bu(float x) {
    hb h = __float2bfloat16(x);
    unsigned short u;
    __builtin_memcpy(&u, &h, 2);
    return u;
}

// ---------------- reductions ----------------
__device__ __forceinline__ float blockSum256(float v) {
    __shared__ float red[4];
    int lane = threadIdx.x & 63, wid = threadIdx.x >> 6;
#pragma unroll
    for (int o = 32; o > 0; o >>= 1) v += __shfl_down(v, o, 64);
    if (lane == 0) red[wid] = v;
    __syncthreads();
    float s = red[0] + red[1] + red[2] + red[3];
    __syncthreads();
    return s;
}
__device__ __forceinline__ float blockMax256(float v) {
    __shared__ float red[4];
    int lane = threadIdx.x & 63, wid = threadIdx.x >> 6;
#pragma unroll
    for (int o = 32; o > 0; o >>= 1) v = fmaxf(v, __shfl_down(v, o, 64));
    if (lane == 0) red[wid] = v;
    __syncthreads();
    float s = fmaxf(fmaxf(red[0], red[1]), fmaxf(red[2], red[3]));
    __syncthreads();
    return s;
}

// ---------------- fused embedding gather + rmsnorm1 ----------------
__global__ void k_embedn(const int* __restrict__ tokens, const float* __restrict__ emb,
                         const float* __restrict__ w, float* __restrict__ X,
                         hb* __restrict__ h1b) {
    int t = blockIdx.x, tid = threadIdx.x;
    int tok = tokens[t];
    float4 v = ((const float4*)(emb + (size_t)tok * CD))[tid];
    ((float4*)(X + (size_t)t * CD))[tid] = v;
    float ss = v.x * v.x + v.y * v.y + v.z * v.z + v.w * v.w;
    float tot = blockSum256(ss);
    float sc = rsqrtf(tot / CD + CEPS);
    float4 wv = ((const float4*)w)[tid];
    hb* o = h1b + (size_t)t * CD + tid * 4;
    o[0] = __float2bfloat16(v.x * sc * wv.x);
    o[1] = __float2bfloat16(v.y * sc * wv.y);
    o[2] = __float2bfloat16(v.z * sc * wv.z);
    o[3] = __float2bfloat16(v.w * sc * wv.w);
}

// ---------------- rmsnorm (bf16 out) ----------------
__global__ void k_rmsnorm_b(const float* __restrict__ in, const float* __restrict__ w,
                            hb* __restrict__ out) {
    int t = blockIdx.x;
    const float* row = in + (size_t)t * CD;
    float ss = 0.f;
    for (int i = threadIdx.x; i < CD; i += 256) { float v = row[i]; ss += v * v; }
    float tot = blockSum256(ss);
    float sc = rsqrtf(tot / CD + CEPS);
    for (int i = threadIdx.x; i < CD; i += 256)
        out[(size_t)t * CD + i] = __float2bfloat16(row[i] * sc * w[i]);
}

// ---------------- DUAL up-proj GEMM: 128x64 tile, BK=32, 3-buffer counted-vmcnt ----------------
// 3-deep LDS pipeline (48 KB -> still 3 blocks/CU), prefetch 2 tiles ahead,
// raw s_barrier + vmcnt(4): the newest tile's 4 loads stay in flight across
// the barrier (never drain-0 in the steady loop). Sync pattern proven correct
// in round 8; here occupancy is preserved (r8's regression was the 72KB/128-AGPR
// occupancy loss, not the pipeline).
template<bool GATHER>
__global__ __launch_bounds__(256, 3)
void k_mfd(const hb* __restrict__ A, int lda,
           const hb* __restrict__ B1g, const hb* __restrict__ B3g, int ldb, long sB,
           hb* __restrict__ Cb, int ldc,
           const int* __restrict__ lists, const int* __restrict__ offs,
           int M, int N, int K) {
    unsigned gx = gridDim.x, gy = gridDim.y;
    unsigned nb = gx * gy * gridDim.z;
    unsigned a0id = blockIdx.x + gx * (blockIdx.y + gy * blockIdx.z);
    unsigned wfl = (a0id & 7) * (nb >> 3) + (a0id >> 3);
    unsigned bx = wfl % gx; unsigned tt = wfl / gx;
    unsigned by = tt % gy;  unsigned bz = tt / gy;

    int e = bz;
    const hb* B1 = B1g + (size_t)e * sB;
    const hb* B3 = B3g + (size_t)e * sB;
    int base = 0, cnt = M;
    if (offs) { base = offs[e]; cnt = offs[e + 1] - base; }
    int row0 = by * 128;
    if (row0 >= cnt) return;
    int col0 = bx * 64;

    constexpr int ASZ = 128 * 32, BSZ = 64 * 32;
    __shared__ hb As[3 * ASZ];
    __shared__ hb Bs1[3 * BSZ];
    __shared__ hb Bs3[3 * BSZ];

    int tid = threadIdx.x;
    int rA = tid >> 2;
    int kq = (((tid & 3) ^ ((rA >> 1) & 3)) * 8);

    auto arowOf = [&](int r) -> size_t {
        int gr = row0 + r; gr = gr < cnt ? gr : cnt - 1;
        if (GATHER) return (size_t)lists[base + gr];
        return (size_t)(base + gr);
    };
    const hb* aS0 = A + arowOf(rA) * lda + kq;
    const hb* aS1 = A + arowOf(64 + rA) * lda + kq;
    const hb* b1S = B1 + (size_t)(col0 + rA) * ldb + kq;
    const hb* b3S = B3 + (size_t)(col0 + rA) * ldb + kq;

    auto stage = [&](int buf, int k0) {
        gload16(aS0 + k0, As + buf * ASZ + tid * 8);
        gload16(aS1 + k0, As + buf * ASZ + (256 + tid) * 8);
        gload16(b1S + k0, Bs1 + buf * BSZ + tid * 8);
        gload16(b3S + k0, Bs3 + buf * BSZ + tid * 8);
    };

    int lane = tid & 63, wid = tid >> 6;
    int wr = wid & 1, wc = wid >> 1;
    int lrow = lane & 15;
    int lk = (((lane >> 4) ^ ((lrow >> 1) & 3)) * 8);

    f32x4 acc1[4][2], acc3[4][2];
#pragma unroll
    for (int m = 0; m < 4; ++m)
#pragma unroll
        for (int n = 0; n < 2; ++n) {
            acc1[m][n] = (f32x4){0.f, 0.f, 0.f, 0.f};
            acc3[m][n] = (f32x4){0.f, 0.f, 0.f, 0.f};
        }

    // prologue: stage tiles 0 and 1; wait tile 0 only (tile 1 stays in flight)
    stage(0, 0);
    if (K > 32) {
        stage(1, 32);
        WAITV4;
    } else {
        WAITV0;
    }
    __builtin_amdgcn_s_barrier();
    CFENCE;

    int cur = 0;
    for (int k0 = 0; k0 < K; k0 += 32) {
        int pre = cur + 2; if (pre >= 3) pre -= 3;
        bool deep = (k0 + 64 < K);
        if (deep) stage(pre, k0 + 64);

        const hb* Ac = As + cur * ASZ;
        const hb* B1c = Bs1 + cur * BSZ;
        const hb* B3c = Bs3 + cur * BSZ;
        bf16x8 af[4], bf1[2], bf3[2];
#pragma unroll
        for (int m = 0; m < 4; ++m)
            af[m] = *(const bf16x8*)(Ac + (size_t)(wr * 64 + m * 16 + lrow) * 32 + lk);
#pragma unroll
        for (int n = 0; n < 2; ++n) {
            bf1[n] = *(const bf16x8*)(B1c + (size_t)(wc * 32 + n * 16 + lrow) * 32 + lk);
            bf3[n] = *(const bf16x8*)(B3c + (size_t)(wc * 32 + n * 16 + lrow) * 32 + lk);
        }
        __builtin_amdgcn_s_setprio(1);
#pragma unroll
        for (int m = 0; m < 4; ++m)
#pragma unroll
            for (int n = 0; n < 2; ++n) {
                acc1[m][n] = __builtin_amdgcn_mfma_f32_16x16x32_bf16(af[m], bf1[n], acc1[m][n], 0, 0, 0);
                acc3[m][n] = __builtin_amdgcn_mfma_f32_16x16x32_bf16(af[m], bf3[n], acc3[m][n], 0, 0, 0);
            }
        __builtin_amdgcn_s_setprio(0);

        if (deep) {
            WAITV4;                 // next tile landed; tile-after stays in flight
        } else if (k0 + 32 < K) {
            WAITV0;                 // drain last prefetch
        }
        __builtin_amdgcn_s_barrier();
        CFENCE;
        cur += 1; if (cur >= 3) cur -= 3;
    }

    int lr4 = ((lane >> 4) & 3) * 4;
#pragma unroll
    for (int m = 0; m < 4; ++m) {
#pragma unroll
        for (int q = 0; q < 4; ++q) {
            int r = row0 + wr * 64 + m * 16 + lr4 + q;
            if (r >= cnt) continue;
            size_t orow = (size_t)(base + r) * ldc;
#pragma unroll
            for (int n = 0; n < 2; ++n) {
                int cc = col0 + wc * 32 + n * 16 + (lane & 15);
                float x = acc1[m][n][q], y = acc3[m][n][q];
                float v = x / (1.f + __expf(-x)) * y;
                Cb[orow + cc] = __float2bfloat16(v);
            }
        }
    }
}

// ---------------- non-dual GEMM: 128x64 tile, BK=64, 4 waves, 3 blocks/CU ----------------
__global__ __launch_bounds__(256, 3)
void k_mf64n(const hb* __restrict__ A, int lda,
             const hb* __restrict__ Bg, int ldb, long sB,
             hb* __restrict__ Cb, int ldc,
             const int* __restrict__ offs,
             int M, int N, int K) {
    unsigned gx = gridDim.x, gy = gridDim.y;
    unsigned nb = gx * gy * gridDim.z;
    unsigned a0id = blockIdx.x + gx * (blockIdx.y + gy * blockIdx.z);
    unsigned wfl = (a0id & 7) * (nb >> 3) + (a0id >> 3);
    unsigned bx = wfl % gx; unsigned tt = wfl / gx;
    unsigned by = tt % gy;  unsigned bz = tt / gy;

    int e = bz;
    const hb* B = Bg + (size_t)e * sB;
    int base = 0, cnt = M;
    if (offs) { base = offs[e]; cnt = offs[e + 1] - base; }
    int row0 = by * 128;
    if (row0 >= cnt) return;
    int col0 = bx * 64;

    __shared__ hb As[2][128 * 64];
    __shared__ hb Bs[2][64 * 64];

    int tid = threadIdx.x;
    int rr = tid >> 3, c0 = tid & 7;
    int kq = ((c0 ^ (rr & 7)) * 8);

    const hb* aS[4];
    const hb* bS[2];
#pragma unroll
    for (int i = 0; i < 4; ++i) {
        int gr = row0 + i * 32 + rr; gr = gr < cnt ? gr : cnt - 1;
        aS[i] = A + (size_t)(base + gr) * lda + kq;
    }
#pragma unroll
    for (int j = 0; j < 2; ++j)
        bS[j] = B + (size_t)(col0 + j * 32 + rr) * ldb + kq;

    auto stage = [&](int buf, int k0) {
#pragma unroll
        for (int i = 0; i < 4; ++i)
            gload16(aS[i] + k0, As[buf] + (i * 256 + tid) * 8);
#pragma unroll
        for (int j = 0; j < 2; ++j)
            gload16(bS[j] + k0, Bs[buf] + (j * 256 + tid) * 8);
    };

    int lane = tid & 63, wid = tid >> 6;
    int wr = wid & 1, wc = wid >> 1;
    int lrow = lane & 15;
    int lsw = lrow & 7;

    f32x4 acc[4][2];
#pragma unroll
    for (int m = 0; m < 4; ++m)
#pragma unroll
        for (int n = 0; n < 2; ++n)
            acc[m][n] = (f32x4){0.f, 0.f, 0.f, 0.f};

    stage(0, 0);
    __syncthreads();
    int cur = 0;

    for (int k0 = 0; k0 < K; k0 += 64) {
        if (k0 + 64 < K) stage(cur ^ 1, k0 + 64);
#pragma unroll
        for (int h = 0; h < 2; ++h) {
            int sc = ((h * 4 + (lane >> 4)) ^ lsw) * 8;
            bf16x8 af[4], bf[2];
#pragma unroll
            for (int m = 0; m < 4; ++m)
                af[m] = *(const bf16x8*)(As[cur] + (size_t)(wr * 64 + m * 16 + lrow) * 64 + sc);
#pragma unroll
            for (int n = 0; n < 2; ++n)
                bf[n] = *(const bf16x8*)(Bs[cur] + (size_t)(wc * 32 + n * 16 + lrow) * 64 + sc);
            __builtin_amdgcn_s_setprio(1);
#pragma unroll
            for (int m = 0; m < 4; ++m)
#pragma unroll
                for (int n = 0; n < 2; ++n)
                    acc[m][n] = __builtin_amdgcn_mfma_f32_16x16x32_bf16(af[m], bf[n], acc[m][n], 0, 0, 0);
            __builtin_amdgcn_s_setprio(0);
        }
        __syncthreads();
        cur ^= 1;
    }

    int lr4 = ((lane >> 4) & 3) * 4;
#pragma unroll
    for (int m = 0; m < 4; ++m) {
#pragma unroll
        for (int q = 0; q < 4; ++q) {
            int r = row0 + wr * 64 + m * 16 + lr4 + q;
            if (r >= cnt) continue;
            size_t orow = (size_t)(base + r) * ldc;
#pragma unroll
            for (int n = 0; n < 2; ++n) {
                int cc = col0 + wc * 32 + n * 16 + (lane & 15);
                Cb[orow + cc] = __float2bfloat16(acc[m][n][q]);
            }
        }
    }
}

// ---------------- bf16 MFMA GEMM: 128x128 tile, BK=64, 4 waves (attention) ----------------
template<int EPI>
__global__ __launch_bounds__(256, 2)
void k_mf64(const hb* __restrict__ A, int lda, long sA1, long sA2,
            const hb* __restrict__ B1g, int ldb, long sB1, long sB2,
            const float* __restrict__ Cin, float* __restrict__ Cf, hb* __restrict__ Cb,
            int ldc, long sC1, long sC2,
            const int* __restrict__ offs,
            int M, int N, int K, int Zi, float alpha) {
    unsigned gx = gridDim.x, gy = gridDim.y;
    unsigned nb = gx * gy * gridDim.z;
    unsigned a0id = blockIdx.x + gx * (blockIdx.y + gy * blockIdx.z);
    unsigned wfl = (a0id & 7) * (nb >> 3) + (a0id >> 3);
    unsigned bx = wfl % gx; unsigned tt = wfl / gx;
    unsigned by = tt % gy;  unsigned bz = tt / gy;

    int z = bz, z1 = z / Zi, z2 = z % Zi;
    A += (size_t)z1 * sA1 + (size_t)z2 * sA2;
    const hb* B1 = B1g + (size_t)z1 * sB1 + (size_t)z2 * sB2;
    long coff = (size_t)z1 * sC1 + (size_t)z2 * sC2;
    if (Cf) Cf += coff;
    if (Cb) Cb += coff;
    if (Cin) Cin += coff;

    int base = 0, cnt = M;
    if (offs) { base = offs[z]; cnt = offs[z + 1] - base; }
    int row0 = by * 128;
    if (row0 >= cnt) return;
    int col0 = bx * 128;

    __shared__ hb As[2][128 * 64];
    __shared__ hb Bs[2][128 * 64];

    int tid = threadIdx.x;
    int rr = tid >> 3;
    int c0 = tid & 7;
    int kq = ((c0 ^ (rr & 7)) * 8);

    const hb* aS[4];
    const hb* bS[4];
#pragma unroll
    for (int i = 0; i < 4; ++i) {
        int gr = row0 + i * 32 + rr; gr = gr < cnt ? gr : cnt - 1;
        aS[i] = A + (size_t)(base + gr) * lda + kq;
        bS[i] = B1 + (size_t)(col0 + i * 32 + rr) * ldb + kq;
    }

    auto stage = [&](int buf, int k0) {
#pragma unroll
        for (int i = 0; i < 4; ++i) {
            gload16(aS[i] + k0, As[buf] + (i * 256 + tid) * 8);
            gload16(bS[i] + k0, Bs[buf] + (i * 256 + tid) * 8);
        }
    };

    int lane = tid & 63, wid = tid >> 6;
    int wr = wid >> 1, wc = wid & 1;
    int lrow = lane & 15;
    int lsw = lrow & 7;

    f32x4 acc[4][4];
#pragma unroll
    for (int m = 0; m < 4; ++m)
#pragma unroll
        for (int n = 0; n < 4; ++n)
            acc[m][n] = (f32x4){0.f, 0.f, 0.f, 0.f};

    stage(0, 0);
    __syncthreads();
    int cur = 0;

    for (int k0 = 0; k0 < K; k0 += 64) {
        if (k0 + 64 < K) stage(cur ^ 1, k0 + 64);
#pragma unroll
        for (int h = 0; h < 2; ++h) {
            int sc = ((h * 4 + (lane >> 4)) ^ lsw) * 8;
            bf16x8 af[4], bf[4];
#pragma unroll
            for (int m = 0; m < 4; ++m)
                af[m] = *(const bf16x8*)(As[cur] + (size_t)(wr * 64 + m * 16 + lrow) * 64 + sc);
#pragma unroll
            for (int n = 0; n < 4; ++n)
                bf[n] = *(const bf16x8*)(Bs[cur] + (size_t)(wc * 64 + n * 16 + lrow) * 64 + sc);
            __builtin_amdgcn_s_setprio(1);
#pragma unroll
            for (int m = 0; m < 4; ++m)
#pragma unroll
                for (int n = 0; n < 4; ++n)
                    acc[m][n] = __builtin_amdgcn_mfma_f32_16x16x32_bf16(af[m], bf[n], acc[m][n], 0, 0, 0);
            __builtin_amdgcn_s_setprio(0);
        }
        __syncthreads();
        cur ^= 1;
    }

    int lr4 = ((lane >> 4) & 3) * 4;
#pragma unroll
    for (int m = 0; m < 4; ++m) {
#pragma unroll
        for (int q = 0; q < 4; ++q) {
            int r = row0 + wr * 64 + m * 16 + lr4 + q;
            if (r >= cnt) continue;
            size_t orow = (size_t)(base + r) * ldc;
#pragma unroll
            for (int n = 0; n < 4; ++n) {
                int cc = col0 + wc * 64 + n * 16 + (lane & 15);
                float v = alpha * acc[m][n][q];
                if constexpr (EPI == 0) {
                    Cb[orow + cc] = __float2bfloat16(v);
                } else {
                    Cf[orow + cc] = v + Cin[orow + cc];
                }
            }
        }
    }
}

// ---------------- vectorized transpose-convert tile ----------------
__device__ __forceinline__ void cvtv_tile(const float* __restrict__ in, hb* __restrict__ out,
                                          int R, int C, int r0, int c0) {
    __shared__ float t[64][69];
    int tid = threadIdx.x;
    int lr = tid >> 4, f4c = tid & 15;
#pragma unroll
    for (int j = 0; j < 4; ++j) {
        int r = lr + 16 * j;
        float4 v = *(const float4*)(in + (size_t)(r0 + r) * C + c0 + f4c * 4);
        t[r][f4c * 4] = v.x; t[r][f4c * 4 + 1] = v.y;
        t[r][f4c * 4 + 2] = v.z; t[r][f4c * 4 + 3] = v.w;
    }
    __syncthreads();
    int r4 = tid & 15, lc = tid >> 4;
#pragma unroll
    for (int j = 0; j < 4; ++j) {
        int c = lc + 16 * j;
        ushort4 u;
        u.x = f2bu(t[r4 * 4][c]);
        u.y = f2bu(t[r4 * 4 + 1][c]);
        u.z = f2bu(t[r4 * 4 + 2][c]);
        u.w = f2bu(t[r4 * 4 + 3][c]);
        *(ushort4*)(out + (size_t)(c0 + c) * R + r0 + r4 * 4) = u;
    }
}

// ---- all 4 attention weight converts in ONE launch (640 blocks) ----
__global__ void k_cvtattn(const float* __restrict__ Wq, const float* __restrict__ Wk,
                          const float* __restrict__ Wv, const float* __restrict__ Wo,
                          hb* __restrict__ Wqkvt, hb* __restrict__ Wot) {
    int b = blockIdx.x;
    const float* src; hb* dst; int R, C, local;
    if (b < 256)      { src = Wq; dst = Wqkvt;                              R = CD; C = CD;   local = b; }
    else if (b < 320) { src = Wk; dst = Wqkvt + (size_t)CD * CD;            R = CD; C = CDKV; local = b - 256; }
    else if (b < 384) { src = Wv; dst = Wqkvt + (size_t)(CD + CDKV) * CD;   R = CD; C = CDKV; local = b - 320; }
    else              { src = Wo; dst = Wot;                                R = CD; C = CD;   local = b - 384; }
    int nbx = C >> 6;
    cvtv_tile(src, dst, R, C, (local / nbx) * 64, (local % nbx) * 64);
}

// ---- all 6 MoE weight converts in ONE launch (12672 blocks) ----
__global__ void k_cvtmoe(const float* __restrict__ shw1, const float* __restrict__ shw3,
                         const float* __restrict__ shw2, const float* __restrict__ exw1,
                         const float* __restrict__ exw3, const float* __restrict__ exw2,
                         hb* __restrict__ shw1t, hb* __restrict__ shw3t, hb* __restrict__ shw2t,
                         hb* __restrict__ exw1t, hb* __restrict__ exw3t, hb* __restrict__ exw2t) {
    int b = blockIdx.x;
    const float* src; hb* dst; int R, C, local;
    if (b < 128)       { src = shw1; dst = shw1t; R = CD; C = CF; local = b; }
    else if (b < 256)  { src = shw3; dst = shw3t; R = CD; C = CF; local = b - 128; }
    else if (b < 384)  { src = shw2; dst = shw2t; R = CF; C = CD; local = b - 256; }
    else if (b < 4480) {
        int l = b - 384, e = l >> 7; local = l & 127;
        src = exw1 + (size_t)e * CD * CF; dst = exw1t + (size_t)e * CD * CF; R = CD; C = CF;
    } else if (b < 8576) {
        int l = b - 4480, e = l >> 7; local = l & 127;
        src = exw3 + (size_t)e * CD * CF; dst = exw3t + (size_t)e * CD * CF; R = CD; C = CF;
    } else {
        int l = b - 8576, e = l >> 7; local = l & 127;
        src = exw2 + (size_t)e * CF * CD; dst = exw2t + (size_t)e * CF * CD; R = CF; C = CD;
    }
    int nbx = C >> 6;
    cvtv_tile(src, dst, R, C, (local / nbx) * 64, (local % nbx) * 64);
}

// f32 transpose (router weight only)
__global__ void k_t32(const float* __restrict__ in, float* __restrict__ out, int R, int C) {
    __shared__ float t[32][33];
    int c0 = blockIdx.x * 32, r0 = blockIdx.y * 32;
    int tx = threadIdx.x & 31, ty = threadIdx.x >> 5;
#pragma unroll
    for (int j = 0; j < 4; ++j)
        t[ty + 8 * j][tx] = in[(size_t)(r0 + ty + 8 * j) * C + c0 + tx];
    __syncthreads();
#pragma unroll
    for (int j = 0; j < 4; ++j)
        out[(size_t)(c0 + ty + 8 * j) * R + r0 + tx] = t[tx][ty + 8 * j];
}
__global__ void k_tb(const hb* __restrict__ qkv, hb* __restrict__ Vct) {
    int b = blockIdx.z;
    const hb* I = qkv + (size_t)b * CS * CQKV + (CD + CDKV);
    hb* O = Vct + (size_t)b * CDKV * CS;
    __shared__ hb t[32][33];
    int d0 = blockIdx.x * 32, s0 = blockIdx.y * 32;
    int tx = threadIdx.x & 31, ty = threadIdx.x >> 5;
#pragma unroll
    for (int j = 0; j < 4; ++j)
        t[ty + 8 * j][tx] = I[(size_t)(s0 + ty + 8 * j) * CQKV + d0 + tx];
    __syncthreads();
#pragma unroll
    for (int j = 0; j < 4; ++j)
        O[(size_t)(d0 + ty + 8 * j) * CS + s0 + tx] = t[tx][ty + 8 * j];
}

// ---------------- softmax rows of CS, bf16 in place ----------------
__global__ void k_softmaxb(hb* __restrict__ P) {
    unsigned* row = (unsigned*)(P + (size_t)blockIdx.x * CS);
    unsigned u0 = row[threadIdx.x * 2], u1 = row[threadIdx.x * 2 + 1];
    float f[4];
    f[0] = __uint_as_float(u0 << 16); f[1] = __uint_as_float(u0 & 0xffff0000u);
    f[2] = __uint_as_float(u1 << 16); f[3] = __uint_as_float(u1 & 0xffff0000u);
    float m = fmaxf(fmaxf(f[0], f[1]), fmaxf(f[2], f[3]));
    m = blockMax256(m);
    float s = 0.f;
#pragma unroll
    for (int i = 0; i < 4; ++i) { f[i] = __expf(f[i] - m); s += f[i]; }
    s = blockSum256(s);
    float inv = 1.f / s;
    unsigned o0 = ((unsigned)f2bu(f[0] * inv)) | (((unsigned)f2bu(f[1] * inv)) << 16);
    unsigned o1 = ((unsigned)f2bu(f[2] * inv)) | (((unsigned)f2bu(f[3] * inv)) << 16);
    row[threadIdx.x * 2] = o0; row[threadIdx.x * 2 + 1] = o1;
}

// ---------------- fused router: logits GEMM + softmax + top-8 (8 tokens/block) ----------------
__global__ void k_router2(const hb* __restrict__ h2b, const float* __restrict__ rwT,
                          const float* __restrict__ bias, int* __restrict__ topi,
                          float* __restrict__ topw, int* __restrict__ counts) {
    __shared__ float hs[8][1032];
    __shared__ float lgs[8][32];
    __shared__ int lc[CE];
    int t0 = blockIdx.x * 8;
    int tid = threadIdx.x;
    if (tid < CE) lc[tid] = 0;
    const unsigned* src = (const unsigned*)(h2b + (size_t)t0 * CD);
#pragma unroll
    for (int it = 0; it < 16; ++it) {
        int j = tid + it * 256;
        unsigned u = src[j];
        int fidx = j * 2;
        int r = fidx >> 10, c = fidx & 1023;
        hs[r][c] = __uint_as_float(u << 16);
        hs[r][c + 1] = __uint_as_float(u & 0xffff0000u);
    }
    __syncthreads();
    int e = tid >> 3, tl = tid & 7;
    const float4* wrow = (const float4*)(rwT + (size_t)e * CD);
    float acc = 0.f;
#pragma unroll 4
    for (int d4 = 0; d4 < 256; ++d4) {
        float4 w = wrow[d4];
        float4 h = *(const float4*)&hs[tl][d4 * 4];
        acc += w.x * h.x + w.y * h.y + w.z * h.z + w.w * h.w;
    }
    lgs[tl][e] = acc + bias[e];
    __syncthreads();
    if (tid < 8) {
        int t = t0 + tid;
        float p[CE];
        float mx = -1e30f;
#pragma unroll
        for (int i = 0; i < CE; ++i) { p[i] = lgs[tid][i]; mx = fmaxf(mx, p[i]); }
        float s = 0.f;
#pragma unroll
        for (int i = 0; i < CE; ++i) { p[i] = __expf(p[i] - mx); s += p[i]; }
        float inv = 1.f / s;
#pragma unroll
        for (int i = 0; i < CE; ++i) p[i] *= inv;
        float vals[CKS]; int ids[CKS];
#pragma unroll
        for (int k = 0; k < CKS; ++k) {
            float bv = -1.f; int bi = 0;
#pragma unroll
            for (int q = 0; q < CE; ++q)
                if (p[q] > bv) { bv = p[q]; bi = q; }
            vals[k] = bv; ids[k] = bi;
#pragma unroll
            for (int q = 0; q < CE; ++q)
                if (q == bi) p[q] = -2.f;
        }
        float ss = 0.f; float ww[CKS];
#pragma unroll
        for (int k = 0; k < CKS; ++k) { ww[k] = __expf(vals[k] - vals[0]); ss += ww[k]; }
        float wiv = 1.f / ss;
#pragma unroll
        for (int k = 0; k < CKS; ++k) {
            topi[t * CKS + k] = ids[k];
            topw[t * CKS + k] = ww[k] * wiv;
            atomicAdd(&lc[ids[k]], 1);
        }
    }
    __syncthreads();
    if (tid < CE && lc[tid]) atomicAdd(&counts[tid], lc[tid]);
}

__global__ void k_scan(const int* __restrict__ counts, int* __restrict__ offs) {
    if (threadIdx.x == 0) {
        int a = 0;
        for (int e = 0; e < CE; ++e) { offs[e] = a; a += counts[e]; }
        offs[CE] = a;
    }
}

__global__ void k_fill(const int* __restrict__ topi,
                       const int* __restrict__ offs, int* __restrict__ cursor,
                       int* __restrict__ lists, int* __restrict__ slot_of) {
    __shared__ int lcnt[CE];
    __shared__ int lbase[CE];
    int tid = threadIdx.x;
    if (tid < CE) lcnt[tid] = 0;
    __syncthreads();
    int idx = blockIdx.x * 256 + tid;
    int e = topi[idx];
    int lpos = atomicAdd(&lcnt[e], 1);
    __syncthreads();
    if (tid < CE) lbase[tid] = lcnt[tid] ? atomicAdd(&cursor[tid], lcnt[tid]) : 0;
    __syncthreads();
    int slot = offs[e] + lbase[e] + lpos;
    lists[slot] = idx >> 3;
    slot_of[idx] = slot;
}

// ---------------- fused combine + residual + final rmsnorm ----------------
__global__ void k_combine(const float* __restrict__ X2, const hb* __restrict__ HSd,
                          const hb* __restrict__ spec_b, const float* __restrict__ topw,
                          const int* __restrict__ slot_of, const float* __restrict__ fnw,
                          float* __restrict__ normX) {
    int t = blockIdx.x, tid = threadIdx.x;
    int d0 = tid * 4;
    __shared__ float wsm[CKS];
    __shared__ int ssm[CKS];
    if (tid < CKS) { wsm[tid] = topw[t * CKS + tid]; ssm[tid] = slot_of[t * CKS + tid]; }
    const float4 x = *(const float4*)(X2 + (size_t)t * CD + d0);
    uint2 hu = *(const uint2*)(HSd + (size_t)t * CD + d0);
    float a0 = x.x + __uint_as_float(hu.x << 16);
    float a1 = x.y + __uint_as_float(hu.x & 0xffff0000u);
    float a2 = x.z + __uint_as_float(hu.y << 16);
    float a3 = x.w + __uint_as_float(hu.y & 0xffff0000u);
    __syncthreads();
#pragma unroll
    for (int k = 0; k < CKS; ++k) {
        float w = wsm[k];
        uint2 u = *(const uint2*)(spec_b + (size_t)ssm[k] * CD + d0);
        a0 += w * __uint_as_float(u.x << 16);
        a1 += w * __uint_as_float(u.x & 0xffff0000u);
        a2 += w * __uint_as_float(u.y << 16);
        a3 += w * __uint_as_float(u.y & 0xffff0000u);
    }
    float ss = a0 * a0 + a1 * a1 + a2 * a2 + a3 * a3;
    float tot = blockSum256(ss);
    float sc = rsqrtf(tot / CD + CEPS);
    float4 o;
    o.x = a0 * sc * fnw[d0];     o.y = a1 * sc * fnw[d0 + 1];
    o.z = a2 * sc * fnw[d0 + 2]; o.w = a3 * sc * fnw[d0 + 3];
    *(float4*)(normX + (size_t)t * CD + d0) = o;
}

// ---------------- parallel pool: 256 blocks, atomic partial sums ----------------
__global__ void k_pool2(const float* __restrict__ nx, float* __restrict__ pooled) {
    int b = blockIdx.x, chunk = blockIdx.y, tid = threadIdx.x;
    const float* basep = nx + ((size_t)b * CS + chunk * 16) * CD;
    float4 acc = {0.f, 0.f, 0.f, 0.f};
    for (int t = 0; t < 16; ++t) {
        float4 v = ((const float4*)(basep + (size_t)t * CD))[tid];
        acc.x += v.x; acc.y += v.y; acc.z += v.z; acc.w += v.w;
    }
    float* p = pooled + b * CD + tid * 4;
    const float inv = 1.f / CS;
    atomicAdd(p,     acc.x * inv);
    atomicAdd(p + 1, acc.y * inv);
    atomicAdd(p + 2, acc.z * inv);
    atomicAdd(p + 3, acc.w * inv);
}

// ---------------- head: per-batch block, blockSum dot per class ----------------
__global__ void k_head2(const float* __restrict__ pooled, const float* __restrict__ cw,
                        const float* __restrict__ cb, float* __restrict__ out) {
    __shared__ float lg[CNC];
    int b = blockIdx.x, tid = threadIdx.x;
    float4 pv = ((const float4*)(pooled + b * CD))[tid];
    for (int c = 0; c < CNC; ++c) {
        int d0 = tid * 4;
        float s = pv.x * cw[(size_t)d0 * CNC + c] + pv.y * cw[(size_t)(d0 + 1) * CNC + c]
                + pv.z * cw[(size_t)(d0 + 2) * CNC + c] + pv.w * cw[(size_t)(d0 + 3) * CNC + c];
        float tot = blockSum256(s);
        if (tid == 0) lg[c] = tot + cb[c];
    }
    __syncthreads();
    if (tid == 0) {
        float mx = -1e30f;
        for (int c = 0; c < CNC; ++c) mx = fmaxf(mx, lg[c]);
        float ex[CNC]; float s = 0.f;
        for (int c = 0; c < CNC; ++c) { ex[c] = __expf(lg[c] - mx); s += ex[c]; }
        for (int c = 0; c < CNC; ++c) out[b * CNC + c] = ex[c] / s;
    }
}

} // namespace

extern "C" void kernel_launch(void* const* d_in, const int* in_sizes, int n_in,
                              void* d_out, int out_size, void* d_ws, size_t ws_size,
                              hipStream_t stream) {
    const int*   tokens = (const int*)d_in[0];
    const float* emb    = (const float*)d_in[1];
    const float* n1w    = (const float*)d_in[2];
    const float* n2w    = (const float*)d_in[3];
    const float* Wq     = (const float*)d_in[4];
    const float* Wk     = (const float*)d_in[5];
    const float* Wv     = (const float*)d_in[6];
    const float* Wo     = (const float*)d_in[7];
    const float* rw     = (const float*)d_in[8];
    const float* ebias  = (const float*)d_in[9];
    const float* shw1   = (const float*)d_in[10];
    const float* shw3   = (const float*)d_in[11];
    const float* shw2   = (const float*)d_in[12];
    const float* exw1   = (const float*)d_in[13];
    const float* exw3   = (const float*)d_in[14];
    const float* exw2   = (const float*)d_in[15];
    const float* fnw    = (const float*)d_in[16];
    const float* clsw   = (const float*)d_in[17];
    const float* clsb   = (const float*)d_in[18];
    float* out = (float*)d_out;

    constexpr size_t MB = 1ull << 20;
    char* base = (char*)d_ws;
    float* X   = (float*)(base);             // 16 MB residual / normX
    float* Xh  = (float*)(base + 16 * MB);   // 16 MB X2
    hb*  HSd   = (hb*)(base + 32 * MB);      // 8 MB
    float* pooled  = (float*)(base + 48 * MB);
    float* topw    = pooled + CB * CD;
    float* rwT     = topw + CT * CKS;
    int* topi    = (int*)(rwT + CE * CD);
    int* lists   = topi + CT * CKS;
    int* slot_of = lists + CT * CKS;
    int* counts  = slot_of + CT * CKS;
    int* cursor  = counts + CE;
    int* offs    = cursor + CE;
    char* pool = base + 50 * MB;
    // attention phase
    hb* h1b   = (hb*)(pool);                 // 8 MB
    hb* QKVb  = (hb*)(pool + 8 * MB);        // 12 MB
    hb* Vct   = (hb*)(pool + 20 * MB);       // 2 MB
    hb* Pb    = (hb*)(pool + 24 * MB);       // 32 MB
    hb* AOb   = (hb*)(pool + 56 * MB);       // 8 MB
    hb* Wqkvt = (hb*)(pool + 64 * MB);       // 3 MB
    hb* Wot   = (hb*)(pool + 67 * MB);       // 2 MB
    // moe phase overlays
    hb* h2b   = (hb*)(pool);                 // 8 MB
    hb* HSb   = (hb*)(pool + 8 * MB);        // 4 MB
    hb* g     = (hb*)(pool + 12 * MB);       // 32 MB
    hb* shw1t = (hb*)(pool + 44 * MB);
    hb* shw3t = (hb*)(pool + 45 * MB);
    hb* shw2t = (hb*)(pool + 46 * MB);
    hb* exw1t = (hb*)(pool + 47 * MB);       // 32 MB
    hb* exw3t = (hb*)(pool + 79 * MB);       // 32 MB
    hb* exw2t = (hb*)(pool + 111 * MB);      // 32 MB (ends 143 MB)
    hb* spec_b = exw1t;                      // 64 MB overlay

    dim3 b256(256);

    // ---- prologue ----
    k_embedn<<<CT, b256, 0, stream>>>(tokens, emb, n1w, X, h1b);
    k_t32<<<dim3(1, CD / 32), b256, 0, stream>>>(rw, rwT, CD, CE);
    k_cvtattn<<<640, b256, 0, stream>>>(Wq, Wk, Wv, Wo, Wqkvt, Wot);

    // ---- attention (bf16 MFMA) ----
    k_mf64<0><<<dim3(CQKV / 128, CT / 128, 1), b256, 0, stream>>>(
        h1b, CD, 0, 0, Wqkvt, CD, 0, 0, nullptr, nullptr, QKVb, CQKV, 0, 0,
        nullptr, CT, CQKV, CD, 1, 1.f);
    k_tb<<<dim3(CDKV / 32, CS / 32, CB), b256, 0, stream>>>(QKVb, Vct);
    k_mf64<0><<<dim3(CS / 128, CS / 128, CB * CH), b256, 0, stream>>>(
        QKVb, CQKV, (long)CS * CQKV, CDK,
        QKVb + CD, CQKV, (long)CS * CQKV, 0,
        nullptr, nullptr, Pb, CS, (long)CH * CS * CS, (long)CS * CS,
        nullptr, CS, CS, CDK, CH, 1.f / 16.f);
    k_softmaxb<<<CB * CH * CS, b256, 0, stream>>>(Pb);
    k_mf64<0><<<dim3(CDK / 128, CS / 128, CB * CH), b256, 0, stream>>>(
        Pb, CS, (long)CH * CS * CS, (long)CS * CS,
        Vct, CS, (long)CDKV * CS, 0,
        nullptr, nullptr, AOb, CD, (long)CS * CD, CDK,
        nullptr, CS, CDK, CS, CH, 1.f);
    k_mf64<4><<<dim3(CD / 128, CT / 128, 1), b256, 0, stream>>>(
        AOb, CD, 0, 0, Wot, CD, 0, 0, X, Xh, nullptr, CD, 0, 0,
        nullptr, CT, CD, CD, 1, 1.f);

    // ---- MoE routing ----
    k_rmsnorm_b<<<CT, b256, 0, stream>>>(Xh, n2w, h2b);
    hipMemsetAsync(counts, 0, (size_t)(CE + CE + CE + 1) * sizeof(int), stream);
    hipMemsetAsync(pooled, 0, (size_t)CB * CD * sizeof(float), stream);
    k_router2<<<CT / 8, b256, 0, stream>>>(h2b, rwT, ebias, topi, topw, counts);
    k_scan<<<1, 64, 0, stream>>>(counts, offs);
    k_fill<<<CT * CKS / 256, b256, 0, stream>>>(topi, offs, cursor, lists, slot_of);

    // MoE weight converts (single launch)
    k_cvtmoe<<<12672, b256, 0, stream>>>(shw1, shw3, shw2, exw1, exw3, exw2,
                                         shw1t, shw3t, shw2t, exw1t, exw3t, exw2t);

    // shared expert up (dual, 128x64, 3-buf pipeline)
    k_mfd<false><<<dim3(CF / 64, CT / 128, 1), b256, 0, stream>>>(
        h2b, CD, shw1t, shw3t, CD, 0, HSb, CF, nullptr, nullptr, CT, CF, CD);
    // routed experts up (dual, gathered, 3-buf pipeline)
    k_mfd<true><<<dim3(CF / 64, CT / 128, CE), b256, 0, stream>>>(
        h2b, CD, exw1t, exw3t, CD, (long)CD * CF, g, CF, lists, offs, 0, CF, CD);
    // shared down
    k_mf64n<<<dim3(CD / 64, CT / 128, 1), b256, 0, stream>>>(
        HSb, CF, shw2t, CF, 0, HSd, CD, nullptr, CT, CD, CF);
    // routed down
    k_mf64n<<<dim3(CD / 64, CT / 128, CE), b256, 0, stream>>>(
        g, CF, exw2t, CF, (long)CF * CD, spec_b, CD, offs, 0, CD, CF);

    // fused combine + residual + final rmsnorm
    k_combine<<<CT, b256, 0, stream>>>(Xh, HSd, spec_b, topw, slot_of, fnw, X);

    // parallel pool + head
    k_pool2<<<dim3(CB, CS / 16), b256, 0, stream>>>(X, pooled);
    k_head2<<<CB, b256, 0, stream>>>(pooled, clsw, clsb, out);
}

// Round 16
// 471.303 us; speedup vs baseline: 1.0278x; 1.0278x over previous
//
#include <hip/hip_runtime.h>
#include <hip/hip_bf16.h>
#include <cmath>

namespace {

constexpr int CB = 4, CS = 1024, CD = 1024, CH = 4, CE = 32, CF = 512;
constexpr int CKS = 8, CNC = 10, CDK = 256, CDKV = 256;
constexpr int CT = CB * CS;
constexpr int CQKV = 1536;
constexpr float CEPS = 1e-6f;

using hb = __hip_bfloat16;
typedef __bf16 bf16x8 __attribute__((ext_vector_type(8)));
typedef float f32x4 __attribute__((ext_vector_type(4)));

__device__ __forceinline__ void gload16(const void* g, void* l) {
    __builtin_amdgcn_global_load_lds((const __attribute__((address_space(1))) void*)g,
                                     (__attribute__((address_space(3))) void*)l, 16, 0, 0);
}

__device__ __forceinline__ unsigned short f2bu(float x) {
    hb h = __float2bfloat16(x);
    unsigned short u;
    __builtin_memcpy(&u, &h, 2);
    return u;
}

// ---------------- reductions ----------------
__device__ __forceinline__ float blockSum256(float v) {
    __shared__ float red[4];
    int lane = threadIdx.x & 63, wid = threadIdx.x >> 6;
#pragma unroll
    for (int o = 32; o > 0; o >>= 1) v += __shfl_down(v, o, 64);
    if (lane == 0) red[wid] = v;
    __syncthreads();
    float s = red[0] + red[1] + red[2] + red[3];
    __syncthreads();
    return s;
}
__device__ __forceinline__ float blockMax256(float v) {
    __shared__ float red[4];
    int lane = threadIdx.x & 63, wid = threadIdx.x >> 6;
#pragma unroll
    for (int o = 32; o > 0; o >>= 1) v = fmaxf(v, __shfl_down(v, o, 64));
    if (lane == 0) red[wid] = v;
    __syncthreads();
    float s = fmaxf(fmaxf(red[0], red[1]), fmaxf(red[2], red[3]));
    __syncthreads();
    return s;
}

// ---------------- fused embedding gather + rmsnorm1 ----------------
__global__ void k_embedn(const int* __restrict__ tokens, const float* __restrict__ emb,
                         const float* __restrict__ w, float* __restrict__ X,
                         hb* __restrict__ h1b) {
    int t = blockIdx.x, tid = threadIdx.x;
    int tok = tokens[t];
    float4 v = ((const float4*)(emb + (size_t)tok * CD))[tid];
    ((float4*)(X + (size_t)t * CD))[tid] = v;
    float ss = v.x * v.x + v.y * v.y + v.z * v.z + v.w * v.w;
    float tot = blockSum256(ss);
    float sc = rsqrtf(tot / CD + CEPS);
    float4 wv = ((const float4*)w)[tid];
    hb* o = h1b + (size_t)t * CD + tid * 4;
    o[0] = __float2bfloat16(v.x * sc * wv.x);
    o[1] = __float2bfloat16(v.y * sc * wv.y);
    o[2] = __float2bfloat16(v.z * sc * wv.z);
    o[3] = __float2bfloat16(v.w * sc * wv.w);
}

// ---------------- rmsnorm (bf16 out) ----------------
__global__ void k_rmsnorm_b(const float* __restrict__ in, const float* __restrict__ w,
                            hb* __restrict__ out) {
    int t = blockIdx.x;
    const float* row = in + (size_t)t * CD;
    float ss = 0.f;
    for (int i = threadIdx.x; i < CD; i += 256) { float v = row[i]; ss += v * v; }
    float tot = blockSum256(ss);
    float sc = rsqrtf(tot / CD + CEPS);
    for (int i = threadIdx.x; i < CD; i += 256)
        out[(size_t)t * CD + i] = __float2bfloat16(row[i] * sc * w[i]);
}

// ---------------- DUAL up-proj GEMM: 128x64 tile, BK=32, 4 waves, 3 blocks/CU ----------------
// 2-buffer dbuf + __syncthreads (known-good 2-phase; counted-vmcnt pipelines
// falsified twice on this family, r8/r15).
template<bool GATHER>
__global__ __launch_bounds__(256, 3)
void k_mfd(const hb* __restrict__ A, int lda,
           const hb* __restrict__ B1g, const hb* __restrict__ B3g, int ldb, long sB,
           hb* __restrict__ Cb, int ldc,
           const int* __restrict__ lists, const int* __restrict__ offs,
           int M, int N, int K) {
    unsigned gx = gridDim.x, gy = gridDim.y;
    unsigned nb = gx * gy * gridDim.z;
    unsigned a0id = blockIdx.x + gx * (blockIdx.y + gy * blockIdx.z);
    unsigned wfl = (a0id & 7) * (nb >> 3) + (a0id >> 3);
    unsigned bx = wfl % gx; unsigned tt = wfl / gx;
    unsigned by = tt % gy;  unsigned bz = tt / gy;

    int e = bz;
    const hb* B1 = B1g + (size_t)e * sB;
    const hb* B3 = B3g + (size_t)e * sB;
    int base = 0, cnt = M;
    if (offs) { base = offs[e]; cnt = offs[e + 1] - base; }
    int row0 = by * 128;
    if (row0 >= cnt) return;
    int col0 = bx * 64;

    __shared__ hb As[2][128 * 32];
    __shared__ hb Bs1[2][64 * 32];
    __shared__ hb Bs3[2][64 * 32];

    int tid = threadIdx.x;
    int rA = tid >> 2;
    int kq = (((tid & 3) ^ ((rA >> 1) & 3)) * 8);

    auto arowOf = [&](int r) -> size_t {
        int gr = row0 + r; gr = gr < cnt ? gr : cnt - 1;
        if (GATHER) return (size_t)lists[base + gr];
        return (size_t)(base + gr);
    };
    const hb* aS0 = A + arowOf(rA) * lda + kq;
    const hb* aS1 = A + arowOf(64 + rA) * lda + kq;
    const hb* b1S = B1 + (size_t)(col0 + rA) * ldb + kq;
    const hb* b3S = B3 + (size_t)(col0 + rA) * ldb + kq;

    auto stage = [&](int buf, int k0) {
        gload16(aS0 + k0, As[buf] + tid * 8);
        gload16(aS1 + k0, As[buf] + (256 + tid) * 8);
        gload16(b1S + k0, Bs1[buf] + tid * 8);
        gload16(b3S + k0, Bs3[buf] + tid * 8);
    };

    int lane = tid & 63, wid = tid >> 6;
    int wr = wid & 1, wc = wid >> 1;
    int lrow = lane & 15;
    int lk = (((lane >> 4) ^ ((lrow >> 1) & 3)) * 8);

    f32x4 acc1[4][2], acc3[4][2];
#pragma unroll
    for (int m = 0; m < 4; ++m)
#pragma unroll
        for (int n = 0; n < 2; ++n) {
            acc1[m][n] = (f32x4){0.f, 0.f, 0.f, 0.f};
            acc3[m][n] = (f32x4){0.f, 0.f, 0.f, 0.f};
        }

    stage(0, 0);
    __syncthreads();
    int cur = 0;

    for (int k0 = 0; k0 < K; k0 += 32) {
        if (k0 + 32 < K) stage(cur ^ 1, k0 + 32);
        bf16x8 af[4], bf1[2], bf3[2];
#pragma unroll
        for (int m = 0; m < 4; ++m)
            af[m] = *(const bf16x8*)(As[cur] + (size_t)(wr * 64 + m * 16 + lrow) * 32 + lk);
#pragma unroll
        for (int n = 0; n < 2; ++n) {
            bf1[n] = *(const bf16x8*)(Bs1[cur] + (size_t)(wc * 32 + n * 16 + lrow) * 32 + lk);
            bf3[n] = *(const bf16x8*)(Bs3[cur] + (size_t)(wc * 32 + n * 16 + lrow) * 32 + lk);
        }
        __builtin_amdgcn_s_setprio(1);
#pragma unroll
        for (int m = 0; m < 4; ++m)
#pragma unroll
            for (int n = 0; n < 2; ++n) {
                acc1[m][n] = __builtin_amdgcn_mfma_f32_16x16x32_bf16(af[m], bf1[n], acc1[m][n], 0, 0, 0);
                acc3[m][n] = __builtin_amdgcn_mfma_f32_16x16x32_bf16(af[m], bf3[n], acc3[m][n], 0, 0, 0);
            }
        __builtin_amdgcn_s_setprio(0);
        __syncthreads();
        cur ^= 1;
    }

    int lr4 = ((lane >> 4) & 3) * 4;
#pragma unroll
    for (int m = 0; m < 4; ++m) {
#pragma unroll
        for (int q = 0; q < 4; ++q) {
            int r = row0 + wr * 64 + m * 16 + lr4 + q;
            if (r >= cnt) continue;
            size_t orow = (size_t)(base + r) * ldc;
#pragma unroll
            for (int n = 0; n < 2; ++n) {
                int cc = col0 + wc * 32 + n * 16 + (lane & 15);
                float x = acc1[m][n][q], y = acc3[m][n][q];
                float v = x / (1.f + __expf(-x)) * y;
                Cb[orow + cc] = __float2bfloat16(v);
            }
        }
    }
}

// ---------------- non-dual GEMM: 128x64 tile, BK=64, 4 waves, 3 blocks/CU ----------------
__global__ __launch_bounds__(256, 3)
void k_mf64n(const hb* __restrict__ A, int lda,
             const hb* __restrict__ Bg, int ldb, long sB,
             hb* __restrict__ Cb, int ldc,
             const int* __restrict__ offs,
             int M, int N, int K) {
    unsigned gx = gridDim.x, gy = gridDim.y;
    unsigned nb = gx * gy * gridDim.z;
    unsigned a0id = blockIdx.x + gx * (blockIdx.y + gy * blockIdx.z);
    unsigned wfl = (a0id & 7) * (nb >> 3) + (a0id >> 3);
    unsigned bx = wfl % gx; unsigned tt = wfl / gx;
    unsigned by = tt % gy;  unsigned bz = tt / gy;

    int e = bz;
    const hb* B = Bg + (size_t)e * sB;
    int base = 0, cnt = M;
    if (offs) { base = offs[e]; cnt = offs[e + 1] - base; }
    int row0 = by * 128;
    if (row0 >= cnt) return;
    int col0 = bx * 64;

    __shared__ hb As[2][128 * 64];
    __shared__ hb Bs[2][64 * 64];

    int tid = threadIdx.x;
    int rr = tid >> 3, c0 = tid & 7;
    int kq = ((c0 ^ (rr & 7)) * 8);

    const hb* aS[4];
    const hb* bS[2];
#pragma unroll
    for (int i = 0; i < 4; ++i) {
        int gr = row0 + i * 32 + rr; gr = gr < cnt ? gr : cnt - 1;
        aS[i] = A + (size_t)(base + gr) * lda + kq;
    }
#pragma unroll
    for (int j = 0; j < 2; ++j)
        bS[j] = B + (size_t)(col0 + j * 32 + rr) * ldb + kq;

    auto stage = [&](int buf, int k0) {
#pragma unroll
        for (int i = 0; i < 4; ++i)
            gload16(aS[i] + k0, As[buf] + (i * 256 + tid) * 8);
#pragma unroll
        for (int j = 0; j < 2; ++j)
            gload16(bS[j] + k0, Bs[buf] + (j * 256 + tid) * 8);
    };

    int lane = tid & 63, wid = tid >> 6;
    int wr = wid & 1, wc = wid >> 1;
    int lrow = lane & 15;
    int lsw = lrow & 7;

    f32x4 acc[4][2];
#pragma unroll
    for (int m = 0; m < 4; ++m)
#pragma unroll
        for (int n = 0; n < 2; ++n)
            acc[m][n] = (f32x4){0.f, 0.f, 0.f, 0.f};

    stage(0, 0);
    __syncthreads();
    int cur = 0;

    for (int k0 = 0; k0 < K; k0 += 64) {
        if (k0 + 64 < K) stage(cur ^ 1, k0 + 64);
#pragma unroll
        for (int h = 0; h < 2; ++h) {
            int sc = ((h * 4 + (lane >> 4)) ^ lsw) * 8;
            bf16x8 af[4], bf[2];
#pragma unroll
            for (int m = 0; m < 4; ++m)
                af[m] = *(const bf16x8*)(As[cur] + (size_t)(wr * 64 + m * 16 + lrow) * 64 + sc);
#pragma unroll
            for (int n = 0; n < 2; ++n)
                bf[n] = *(const bf16x8*)(Bs[cur] + (size_t)(wc * 32 + n * 16 + lrow) * 64 + sc);
            __builtin_amdgcn_s_setprio(1);
#pragma unroll
            for (int m = 0; m < 4; ++m)
#pragma unroll
                for (int n = 0; n < 2; ++n)
                    acc[m][n] = __builtin_amdgcn_mfma_f32_16x16x32_bf16(af[m], bf[n], acc[m][n], 0, 0, 0);
            __builtin_amdgcn_s_setprio(0);
        }
        __syncthreads();
        cur ^= 1;
    }

    int lr4 = ((lane >> 4) & 3) * 4;
#pragma unroll
    for (int m = 0; m < 4; ++m) {
#pragma unroll
        for (int q = 0; q < 4; ++q) {
            int r = row0 + wr * 64 + m * 16 + lr4 + q;
            if (r >= cnt) continue;
            size_t orow = (size_t)(base + r) * ldc;
#pragma unroll
            for (int n = 0; n < 2; ++n) {
                int cc = col0 + wc * 32 + n * 16 + (lane & 15);
                Cb[orow + cc] = __float2bfloat16(acc[m][n][q]);
            }
        }
    }
}

// ---------------- bf16 MFMA GEMM: 128x128 tile, BK=64, 4 waves (attention) ----------------
template<int EPI>
__global__ __launch_bounds__(256, 2)
void k_mf64(const hb* __restrict__ A, int lda, long sA1, long sA2,
            const hb* __restrict__ B1g, int ldb, long sB1, long sB2,
            const float* __restrict__ Cin, float* __restrict__ Cf, hb* __restrict__ Cb,
            int ldc, long sC1, long sC2,
            const int* __restrict__ offs,
            int M, int N, int K, int Zi, float alpha) {
    unsigned gx = gridDim.x, gy = gridDim.y;
    unsigned nb = gx * gy * gridDim.z;
    unsigned a0id = blockIdx.x + gx * (blockIdx.y + gy * blockIdx.z);
    unsigned wfl = (a0id & 7) * (nb >> 3) + (a0id >> 3);
    unsigned bx = wfl % gx; unsigned tt = wfl / gx;
    unsigned by = tt % gy;  unsigned bz = tt / gy;

    int z = bz, z1 = z / Zi, z2 = z % Zi;
    A += (size_t)z1 * sA1 + (size_t)z2 * sA2;
    const hb* B1 = B1g + (size_t)z1 * sB1 + (size_t)z2 * sB2;
    long coff = (size_t)z1 * sC1 + (size_t)z2 * sC2;
    if (Cf) Cf += coff;
    if (Cb) Cb += coff;
    if (Cin) Cin += coff;

    int base = 0, cnt = M;
    if (offs) { base = offs[z]; cnt = offs[z + 1] - base; }
    int row0 = by * 128;
    if (row0 >= cnt) return;
    int col0 = bx * 128;

    __shared__ hb As[2][128 * 64];
    __shared__ hb Bs[2][128 * 64];

    int tid = threadIdx.x;
    int rr = tid >> 3;
    int c0 = tid & 7;
    int kq = ((c0 ^ (rr & 7)) * 8);

    const hb* aS[4];
    const hb* bS[4];
#pragma unroll
    for (int i = 0; i < 4; ++i) {
        int gr = row0 + i * 32 + rr; gr = gr < cnt ? gr : cnt - 1;
        aS[i] = A + (size_t)(base + gr) * lda + kq;
        bS[i] = B1 + (size_t)(col0 + i * 32 + rr) * ldb + kq;
    }

    auto stage = [&](int buf, int k0) {
#pragma unroll
        for (int i = 0; i < 4; ++i) {
            gload16(aS[i] + k0, As[buf] + (i * 256 + tid) * 8);
            gload16(bS[i] + k0, Bs[buf] + (i * 256 + tid) * 8);
        }
    };

    int lane = tid & 63, wid = tid >> 6;
    int wr = wid >> 1, wc = wid & 1;
    int lrow = lane & 15;
    int lsw = lrow & 7;

    f32x4 acc[4][4];
#pragma unroll
    for (int m = 0; m < 4; ++m)
#pragma unroll
        for (int n = 0; n < 4; ++n)
            acc[m][n] = (f32x4){0.f, 0.f, 0.f, 0.f};

    stage(0, 0);
    __syncthreads();
    int cur = 0;

    for (int k0 = 0; k0 < K; k0 += 64) {
        if (k0 + 64 < K) stage(cur ^ 1, k0 + 64);
#pragma unroll
        for (int h = 0; h < 2; ++h) {
            int sc = ((h * 4 + (lane >> 4)) ^ lsw) * 8;
            bf16x8 af[4], bf[4];
#pragma unroll
            for (int m = 0; m < 4; ++m)
                af[m] = *(const bf16x8*)(As[cur] + (size_t)(wr * 64 + m * 16 + lrow) * 64 + sc);
#pragma unroll
            for (int n = 0; n < 4; ++n)
                bf[n] = *(const bf16x8*)(Bs[cur] + (size_t)(wc * 64 + n * 16 + lrow) * 64 + sc);
            __builtin_amdgcn_s_setprio(1);
#pragma unroll
            for (int m = 0; m < 4; ++m)
#pragma unroll
                for (int n = 0; n < 4; ++n)
                    acc[m][n] = __builtin_amdgcn_mfma_f32_16x16x32_bf16(af[m], bf[n], acc[m][n], 0, 0, 0);
            __builtin_amdgcn_s_setprio(0);
        }
        __syncthreads();
        cur ^= 1;
    }

    int lr4 = ((lane >> 4) & 3) * 4;
#pragma unroll
    for (int m = 0; m < 4; ++m) {
#pragma unroll
        for (int q = 0; q < 4; ++q) {
            int r = row0 + wr * 64 + m * 16 + lr4 + q;
            if (r >= cnt) continue;
            size_t orow = (size_t)(base + r) * ldc;
#pragma unroll
            for (int n = 0; n < 4; ++n) {
                int cc = col0 + wc * 64 + n * 16 + (lane & 15);
                float v = alpha * acc[m][n][q];
                if constexpr (EPI == 0) {
                    Cb[orow + cc] = __float2bfloat16(v);
                } else {
                    Cf[orow + cc] = v + Cin[orow + cc];
                }
            }
        }
    }
}

// ---------------- vectorized transpose-convert tile ----------------
__device__ __forceinline__ void cvtv_tile(const float* __restrict__ in, hb* __restrict__ out,
                                          int R, int C, int r0, int c0) {
    __shared__ float t[64][69];
    int tid = threadIdx.x;
    int lr = tid >> 4, f4c = tid & 15;
#pragma unroll
    for (int j = 0; j < 4; ++j) {
        int r = lr + 16 * j;
        float4 v = *(const float4*)(in + (size_t)(r0 + r) * C + c0 + f4c * 4);
        t[r][f4c * 4] = v.x; t[r][f4c * 4 + 1] = v.y;
        t[r][f4c * 4 + 2] = v.z; t[r][f4c * 4 + 3] = v.w;
    }
    __syncthreads();
    int r4 = tid & 15, lc = tid >> 4;
#pragma unroll
    for (int j = 0; j < 4; ++j) {
        int c = lc + 16 * j;
        ushort4 u;
        u.x = f2bu(t[r4 * 4][c]);
        u.y = f2bu(t[r4 * 4 + 1][c]);
        u.z = f2bu(t[r4 * 4 + 2][c]);
        u.w = f2bu(t[r4 * 4 + 3][c]);
        *(ushort4*)(out + (size_t)(c0 + c) * R + r0 + r4 * 4) = u;
    }
}

// ---- all 4 attention weight converts in ONE launch (640 blocks) ----
__global__ void k_cvtattn(const float* __restrict__ Wq, const float* __restrict__ Wk,
                          const float* __restrict__ Wv, const float* __restrict__ Wo,
                          hb* __restrict__ Wqkvt, hb* __restrict__ Wot) {
    int b = blockIdx.x;
    const float* src; hb* dst; int R, C, local;
    if (b < 256)      { src = Wq; dst = Wqkvt;                              R = CD; C = CD;   local = b; }
    else if (b < 320) { src = Wk; dst = Wqkvt + (size_t)CD * CD;            R = CD; C = CDKV; local = b - 256; }
    else if (b < 384) { src = Wv; dst = Wqkvt + (size_t)(CD + CDKV) * CD;   R = CD; C = CDKV; local = b - 320; }
    else              { src = Wo; dst = Wot;                                R = CD; C = CD;   local = b - 384; }
    int nbx = C >> 6;
    cvtv_tile(src, dst, R, C, (local / nbx) * 64, (local % nbx) * 64);
}

// ---- all 6 MoE weight converts in ONE launch (12672 blocks) ----
__global__ void k_cvtmoe(const float* __restrict__ shw1, const float* __restrict__ shw3,
                         const float* __restrict__ shw2, const float* __restrict__ exw1,
                         const float* __restrict__ exw3, const float* __restrict__ exw2,
                         hb* __restrict__ shw1t, hb* __restrict__ shw3t, hb* __restrict__ shw2t,
                         hb* __restrict__ exw1t, hb* __restrict__ exw3t, hb* __restrict__ exw2t) {
    int b = blockIdx.x;
    const float* src; hb* dst; int R, C, local;
    if (b < 128)       { src = shw1; dst = shw1t; R = CD; C = CF; local = b; }
    else if (b < 256)  { src = shw3; dst = shw3t; R = CD; C = CF; local = b - 128; }
    else if (b < 384)  { src = shw2; dst = shw2t; R = CF; C = CD; local = b - 256; }
    else if (b < 4480) {
        int l = b - 384, e = l >> 7; local = l & 127;
        src = exw1 + (size_t)e * CD * CF; dst = exw1t + (size_t)e * CD * CF; R = CD; C = CF;
    } else if (b < 8576) {
        int l = b - 4480, e = l >> 7; local = l & 127;
        src = exw3 + (size_t)e * CD * CF; dst = exw3t + (size_t)e * CD * CF; R = CD; C = CF;
    } else {
        int l = b - 8576, e = l >> 7; local = l & 127;
        src = exw2 + (size_t)e * CF * CD; dst = exw2t + (size_t)e * CF * CD; R = CF; C = CD;
    }
    int nbx = C >> 6;
    cvtv_tile(src, dst, R, C, (local / nbx) * 64, (local % nbx) * 64);
}

// f32 transpose (router weight only)
__global__ void k_t32(const float* __restrict__ in, float* __restrict__ out, int R, int C) {
    __shared__ float t[32][33];
    int c0 = blockIdx.x * 32, r0 = blockIdx.y * 32;
    int tx = threadIdx.x & 31, ty = threadIdx.x >> 5;
#pragma unroll
    for (int j = 0; j < 4; ++j)
        t[ty + 8 * j][tx] = in[(size_t)(r0 + ty + 8 * j) * C + c0 + tx];
    __syncthreads();
#pragma unroll
    for (int j = 0; j < 4; ++j)
        out[(size_t)(c0 + ty + 8 * j) * R + r0 + tx] = t[tx][ty + 8 * j];
}
__global__ void k_tb(const hb* __restrict__ qkv, hb* __restrict__ Vct) {
    int b = blockIdx.z;
    const hb* I = qkv + (size_t)b * CS * CQKV + (CD + CDKV);
    hb* O = Vct + (size_t)b * CDKV * CS;
    __shared__ hb t[32][33];
    int d0 = blockIdx.x * 32, s0 = blockIdx.y * 32;
    int tx = threadIdx.x & 31, ty = threadIdx.x >> 5;
#pragma unroll
    for (int j = 0; j < 4; ++j)
        t[ty + 8 * j][tx] = I[(size_t)(s0 + ty + 8 * j) * CQKV + d0 + tx];
    __syncthreads();
#pragma unroll
    for (int j = 0; j < 4; ++j)
        O[(size_t)(d0 + ty + 8 * j) * CS + s0 + tx] = t[tx][ty + 8 * j];
}

// ---------------- softmax rows of CS, bf16 in place ----------------
__global__ void k_softmaxb(hb* __restrict__ P) {
    unsigned* row = (unsigned*)(P + (size_t)blockIdx.x * CS);
    unsigned u0 = row[threadIdx.x * 2], u1 = row[threadIdx.x * 2 + 1];
    float f[4];
    f[0] = __uint_as_float(u0 << 16); f[1] = __uint_as_float(u0 & 0xffff0000u);
    f[2] = __uint_as_float(u1 << 16); f[3] = __uint_as_float(u1 & 0xffff0000u);
    float m = fmaxf(fmaxf(f[0], f[1]), fmaxf(f[2], f[3]));
    m = blockMax256(m);
    float s = 0.f;
#pragma unroll
    for (int i = 0; i < 4; ++i) { f[i] = __expf(f[i] - m); s += f[i]; }
    s = blockSum256(s);
    float inv = 1.f / s;
    unsigned o0 = ((unsigned)f2bu(f[0] * inv)) | (((unsigned)f2bu(f[1] * inv)) << 16);
    unsigned o1 = ((unsigned)f2bu(f[2] * inv)) | (((unsigned)f2bu(f[3] * inv)) << 16);
    row[threadIdx.x * 2] = o0; row[threadIdx.x * 2 + 1] = o1;
}

// ---------------- fused router: logits GEMM + softmax + top-8 (8 tokens/block) ----------------
__global__ void k_router2(const hb* __restrict__ h2b, const float* __restrict__ rwT,
                          const float* __restrict__ bias, int* __restrict__ topi,
                          float* __restrict__ topw, int* __restrict__ counts) {
    __shared__ float hs[8][1032];
    __shared__ float lgs[8][32];
    __shared__ int lc[CE];
    int t0 = blockIdx.x * 8;
    int tid = threadIdx.x;
    if (tid < CE) lc[tid] = 0;
    const unsigned* src = (const unsigned*)(h2b + (size_t)t0 * CD);
#pragma unroll
    for (int it = 0; it < 16; ++it) {
        int j = tid + it * 256;
        unsigned u = src[j];
        int fidx = j * 2;
        int r = fidx >> 10, c = fidx & 1023;
        hs[r][c] = __uint_as_float(u << 16);
        hs[r][c + 1] = __uint_as_float(u & 0xffff0000u);
    }
    __syncthreads();
    int e = tid >> 3, tl = tid & 7;
    const float4* wrow = (const float4*)(rwT + (size_t)e * CD);
    float acc = 0.f;
#pragma unroll 4
    for (int d4 = 0; d4 < 256; ++d4) {
        float4 w = wrow[d4];
        float4 h = *(const float4*)&hs[tl][d4 * 4];
        acc += w.x * h.x + w.y * h.y + w.z * h.z + w.w * h.w;
    }
    lgs[tl][e] = acc + bias[e];
    __syncthreads();
    if (tid < 8) {
        int t = t0 + tid;
        float p[CE];
        float mx = -1e30f;
#pragma unroll
        for (int i = 0; i < CE; ++i) { p[i] = lgs[tid][i]; mx = fmaxf(mx, p[i]); }
        float s = 0.f;
#pragma unroll
        for (int i = 0; i < CE; ++i) { p[i] = __expf(p[i] - mx); s += p[i]; }
        float inv = 1.f / s;
#pragma unroll
        for (int i = 0; i < CE; ++i) p[i] *= inv;
        float vals[CKS]; int ids[CKS];
#pragma unroll
        for (int k = 0; k < CKS; ++k) {
            float bv = -1.f; int bi = 0;
#pragma unroll
            for (int q = 0; q < CE; ++q)
                if (p[q] > bv) { bv = p[q]; bi = q; }
            vals[k] = bv; ids[k] = bi;
#pragma unroll
            for (int q = 0; q < CE; ++q)
                if (q == bi) p[q] = -2.f;
        }
        float ss = 0.f; float ww[CKS];
#pragma unroll
        for (int k = 0; k < CKS; ++k) { ww[k] = __expf(vals[k] - vals[0]); ss += ww[k]; }
        float wiv = 1.f / ss;
#pragma unroll
        for (int k = 0; k < CKS; ++k) {
            topi[t * CKS + k] = ids[k];
            topw[t * CKS + k] = ww[k] * wiv;
            atomicAdd(&lc[ids[k]], 1);
        }
    }
    __syncthreads();
    if (tid < CE && lc[tid]) atomicAdd(&counts[tid], lc[tid]);
}

__global__ void k_scan(const int* __restrict__ counts, int* __restrict__ offs) {
    if (threadIdx.x == 0) {
        int a = 0;
        for (int e = 0; e < CE; ++e) { offs[e] = a; a += counts[e]; }
        offs[CE] = a;
    }
}

__global__ void k_fill(const int* __restrict__ topi,
                       const int* __restrict__ offs, int* __restrict__ cursor,
                       int* __restrict__ lists, int* __restrict__ slot_of) {
    __shared__ int lcnt[CE];
    __shared__ int lbase[CE];
    int tid = threadIdx.x;
    if (tid < CE) lcnt[tid] = 0;
    __syncthreads();
    int idx = blockIdx.x * 256 + tid;
    int e = topi[idx];
    int lpos = atomicAdd(&lcnt[e], 1);
    __syncthreads();
    if (tid < CE) lbase[tid] = lcnt[tid] ? atomicAdd(&cursor[tid], lcnt[tid]) : 0;
    __syncthreads();
    int slot = offs[e] + lbase[e] + lpos;
    lists[slot] = idx >> 3;
    slot_of[idx] = slot;
}

// ---------------- fused combine + residual + final rmsnorm ----------------
__global__ void k_combine(const float* __restrict__ X2, const hb* __restrict__ HSd,
                          const hb* __restrict__ spec_b, const float* __restrict__ topw,
                          const int* __restrict__ slot_of, const float* __restrict__ fnw,
                          float* __restrict__ normX) {
    int t = blockIdx.x, tid = threadIdx.x;
    int d0 = tid * 4;
    __shared__ float wsm[CKS];
    __shared__ int ssm[CKS];
    if (tid < CKS) { wsm[tid] = topw[t * CKS + tid]; ssm[tid] = slot_of[t * CKS + tid]; }
    const float4 x = *(const float4*)(X2 + (size_t)t * CD + d0);
    uint2 hu = *(const uint2*)(HSd + (size_t)t * CD + d0);
    float a0 = x.x + __uint_as_float(hu.x << 16);
    float a1 = x.y + __uint_as_float(hu.x & 0xffff0000u);
    float a2 = x.z + __uint_as_float(hu.y << 16);
    float a3 = x.w + __uint_as_float(hu.y & 0xffff0000u);
    __syncthreads();
#pragma unroll
    for (int k = 0; k < CKS; ++k) {
        float w = wsm[k];
        uint2 u = *(const uint2*)(spec_b + (size_t)ssm[k] * CD + d0);
        a0 += w * __uint_as_float(u.x << 16);
        a1 += w * __uint_as_float(u.x & 0xffff0000u);
        a2 += w * __uint_as_float(u.y << 16);
        a3 += w * __uint_as_float(u.y & 0xffff0000u);
    }
    float ss = a0 * a0 + a1 * a1 + a2 * a2 + a3 * a3;
    float tot = blockSum256(ss);
    float sc = rsqrtf(tot / CD + CEPS);
    float4 o;
    o.x = a0 * sc * fnw[d0];     o.y = a1 * sc * fnw[d0 + 1];
    o.z = a2 * sc * fnw[d0 + 2]; o.w = a3 * sc * fnw[d0 + 3];
    *(float4*)(normX + (size_t)t * CD + d0) = o;
}

// ---------------- parallel pool: 256 blocks, atomic partial sums ----------------
__global__ void k_pool2(const float* __restrict__ nx, float* __restrict__ pooled) {
    int b = blockIdx.x, chunk = blockIdx.y, tid = threadIdx.x;
    const float* basep = nx + ((size_t)b * CS + chunk * 16) * CD;
    float4 acc = {0.f, 0.f, 0.f, 0.f};
    for (int t = 0; t < 16; ++t) {
        float4 v = ((const float4*)(basep + (size_t)t * CD))[tid];
        acc.x += v.x; acc.y += v.y; acc.z += v.z; acc.w += v.w;
    }
    float* p = pooled + b * CD + tid * 4;
    const float inv = 1.f / CS;
    atomicAdd(p,     acc.x * inv);
    atomicAdd(p + 1, acc.y * inv);
    atomicAdd(p + 2, acc.z * inv);
    atomicAdd(p + 3, acc.w * inv);
}

// ---------------- head: per-batch block, blockSum dot per class ----------------
__global__ void k_head2(const float* __restrict__ pooled, const float* __restrict__ cw,
                        const float* __restrict__ cb, float* __restrict__ out) {
    __shared__ float lg[CNC];
    int b = blockIdx.x, tid = threadIdx.x;
    float4 pv = ((const float4*)(pooled + b * CD))[tid];
    for (int c = 0; c < CNC; ++c) {
        int d0 = tid * 4;
        float s = pv.x * cw[(size_t)d0 * CNC + c] + pv.y * cw[(size_t)(d0 + 1) * CNC + c]
                + pv.z * cw[(size_t)(d0 + 2) * CNC + c] + pv.w * cw[(size_t)(d0 + 3) * CNC + c];
        float tot = blockSum256(s);
        if (tid == 0) lg[c] = tot + cb[c];
    }
    __syncthreads();
    if (tid == 0) {
        float mx = -1e30f;
        for (int c = 0; c < CNC; ++c) mx = fmaxf(mx, lg[c]);
        float ex[CNC]; float s = 0.f;
        for (int c = 0; c < CNC; ++c) { ex[c] = __expf(lg[c] - mx); s += ex[c]; }
        for (int c = 0; c < CNC; ++c) out[b * CNC + c] = ex[c] / s;
    }
}

} // namespace

extern "C" void kernel_launch(void* const* d_in, const int* in_sizes, int n_in,
                              void* d_out, int out_size, void* d_ws, size_t ws_size,
                              hipStream_t stream) {
    const int*   tokens = (const int*)d_in[0];
    const float* emb    = (const float*)d_in[1];
    const float* n1w    = (const float*)d_in[2];
    const float* n2w    = (const float*)d_in[3];
    const float* Wq     = (const float*)d_in[4];
    const float* Wk     = (const float*)d_in[5];
    const float* Wv     = (const float*)d_in[6];
    const float* Wo     = (const float*)d_in[7];
    const float* rw     = (const float*)d_in[8];
    const float* ebias  = (const float*)d_in[9];
    const float* shw1   = (const float*)d_in[10];
    const float* shw3   = (const float*)d_in[11];
    const float* shw2   = (const float*)d_in[12];
    const float* exw1   = (const float*)d_in[13];
    const float* exw3   = (const float*)d_in[14];
    const float* exw2   = (const float*)d_in[15];
    const float* fnw    = (const float*)d_in[16];
    const float* clsw   = (const float*)d_in[17];
    const float* clsb   = (const float*)d_in[18];
    float* out = (float*)d_out;

    constexpr size_t MB = 1ull << 20;
    char* base = (char*)d_ws;
    float* X   = (float*)(base);             // 16 MB residual / normX
    float* Xh  = (float*)(base + 16 * MB);   // 16 MB X2
    hb*  HSd   = (hb*)(base + 32 * MB);      // 8 MB
    float* pooled  = (float*)(base + 48 * MB);
    float* topw    = pooled + CB * CD;
    float* rwT     = topw + CT * CKS;
    int* topi    = (int*)(rwT + CE * CD);
    int* lists   = topi + CT * CKS;
    int* slot_of = lists + CT * CKS;
    int* counts  = slot_of + CT * CKS;
    int* cursor  = counts + CE;
    int* offs    = cursor + CE;
    char* pool = base + 50 * MB;
    // attention phase
    hb* h1b   = (hb*)(pool);                 // 8 MB
    hb* QKVb  = (hb*)(pool + 8 * MB);        // 12 MB
    hb* Vct   = (hb*)(pool + 20 * MB);       // 2 MB
    hb* Pb    = (hb*)(pool + 24 * MB);       // 32 MB
    hb* AOb   = (hb*)(pool + 56 * MB);       // 8 MB
    hb* Wqkvt = (hb*)(pool + 64 * MB);       // 3 MB
    hb* Wot   = (hb*)(pool + 67 * MB);       // 2 MB
    // moe phase overlays
    hb* h2b   = (hb*)(pool);                 // 8 MB
    hb* HSb   = (hb*)(pool + 8 * MB);        // 4 MB
    hb* g     = (hb*)(pool + 12 * MB);       // 32 MB
    hb* shw1t = (hb*)(pool + 44 * MB);
    hb* shw3t = (hb*)(pool + 45 * MB);
    hb* shw2t = (hb*)(pool + 46 * MB);
    hb* exw1t = (hb*)(pool + 47 * MB);       // 32 MB
    hb* exw3t = (hb*)(pool + 79 * MB);       // 32 MB
    hb* exw2t = (hb*)(pool + 111 * MB);      // 32 MB (ends 143 MB)
    hb* spec_b = exw1t;                      // 64 MB overlay

    dim3 b256(256);

    // ---- prologue ----
    k_embedn<<<CT, b256, 0, stream>>>(tokens, emb, n1w, X, h1b);
    k_t32<<<dim3(1, CD / 32), b256, 0, stream>>>(rw, rwT, CD, CE);
    k_cvtattn<<<640, b256, 0, stream>>>(Wq, Wk, Wv, Wo, Wqkvt, Wot);

    // ---- attention (bf16 MFMA) ----
    k_mf64<0><<<dim3(CQKV / 128, CT / 128, 1), b256, 0, stream>>>(
        h1b, CD, 0, 0, Wqkvt, CD, 0, 0, nullptr, nullptr, QKVb, CQKV, 0, 0,
        nullptr, CT, CQKV, CD, 1, 1.f);
    k_tb<<<dim3(CDKV / 32, CS / 32, CB), b256, 0, stream>>>(QKVb, Vct);
    k_mf64<0><<<dim3(CS / 128, CS / 128, CB * CH), b256, 0, stream>>>(
        QKVb, CQKV, (long)CS * CQKV, CDK,
        QKVb + CD, CQKV, (long)CS * CQKV, 0,
        nullptr, nullptr, Pb, CS, (long)CH * CS * CS, (long)CS * CS,
        nullptr, CS, CS, CDK, CH, 1.f / 16.f);
    k_softmaxb<<<CB * CH * CS, b256, 0, stream>>>(Pb);
    k_mf64<0><<<dim3(CDK / 128, CS / 128, CB * CH), b256, 0, stream>>>(
        Pb, CS, (long)CH * CS * CS, (long)CS * CS,
        Vct, CS, (long)CDKV * CS, 0,
        nullptr, nullptr, AOb, CD, (long)CS * CD, CDK,
        nullptr, CS, CDK, CS, CH, 1.f);
    k_mf64<4><<<dim3(CD / 128, CT / 128, 1), b256, 0, stream>>>(
        AOb, CD, 0, 0, Wot, CD, 0, 0, X, Xh, nullptr, CD, 0, 0,
        nullptr, CT, CD, CD, 1, 1.f);

    // ---- MoE routing ----
    k_rmsnorm_b<<<CT, b256, 0, stream>>>(Xh, n2w, h2b);
    hipMemsetAsync(counts, 0, (size_t)(CE + CE + CE + 1) * sizeof(int), stream);
    hipMemsetAsync(pooled, 0, (size_t)CB * CD * sizeof(float), stream);
    k_router2<<<CT / 8, b256, 0, stream>>>(h2b, rwT, ebias, topi, topw, counts);
    k_scan<<<1, 64, 0, stream>>>(counts, offs);
    k_fill<<<CT * CKS / 256, b256, 0, stream>>>(topi, offs, cursor, lists, slot_of);

    // MoE weight converts (single launch)
    k_cvtmoe<<<12672, b256, 0, stream>>>(shw1, shw3, shw2, exw1, exw3, exw2,
                                         shw1t, shw3t, shw2t, exw1t, exw3t, exw2t);

    // shared expert up (dual, 128x64, 3 blocks/CU)
    k_mfd<false><<<dim3(CF / 64, CT / 128, 1), b256, 0, stream>>>(
        h2b, CD, shw1t, shw3t, CD, 0, HSb, CF, nullptr, nullptr, CT, CF, CD);
    // routed experts up (dual, gathered)
    k_mfd<true><<<dim3(CF / 64, CT / 128, CE), b256, 0, stream>>>(
        h2b, CD, exw1t, exw3t, CD, (long)CD * CF, g, CF, lists, offs, 0, CF, CD);
    // shared down
    k_mf64n<<<dim3(CD / 64, CT / 128, 1), b256, 0, stream>>>(
        HSb, CF, shw2t, CF, 0, HSd, CD, nullptr, CT, CD, CF);
    // routed down
    k_mf64n<<<dim3(CD / 64, CT / 128, CE), b256, 0, stream>>>(
        g, CF, exw2t, CF, (long)CF * CD, spec_b, CD, offs, 0, CD, CF);

    // fused combine + residual + final rmsnorm
    k_combine<<<CT, b256, 0, stream>>>(Xh, HSd, spec_b, topw, slot_of, fnw, X);

    // parallel pool + head
    k_pool2<<<dim3(CB, CS / 16), b256, 0, stream>>>(X, pooled);
    k_head2<<<CB, b256, 0, stream>>>(pooled, clsw, clsb, out);
}